// Round 5
// baseline (174.992 us; speedup 1.0000x reference)
//
#include <hip/hip_runtime.h>
#include <stdint.h>

// ---------------------------------------------------------------------------
// HeteNet round 5: R4's LDS-free per-lane dataflow + per-net LDS weight
// staging (double-buffered) to kill redundant per-wave global weight loads.
// Wave = 64 tokens (4 tiles of 16); block = 4 waves = 256 tokens; grid 1024.
// Per net ne: weights (L1 12 KB + L2 8 KB + L3 2 KB = 22.5 KB) staged into
// LDS buf[ne&1]; net ne+1 prefetched into regs during compute, ds_write at
// iteration end, one barrier per net.
// Transposed MFMA: A = frag-ready weights, B = token-frags; sigma-permuted
// W2/W3 k-order makes layer transitions pure in-lane repacking (see R4).
// Biases: b1 folded into K-slot 68 (x[68]=1), b2/b3 folded into acc-init.
// ws layout: wp[56320 shorts] only.
// ---------------------------------------------------------------------------

typedef float v4f __attribute__((ext_vector_type(4)));
typedef short v8s __attribute__((ext_vector_type(8)));

#define WP2_OFF 30720  // shorts; 60 frag-blocks * 512
#define WP3_OFF 51200  // + 40 * 512
#define NSLOT   1408   // uint4 slots per net: L1 768 + L2 512 + L3 128

static __device__ __forceinline__ uint32_t rna_hi(float f) {
    union { float f; uint32_t u; } c; c.f = f;
    return (c.u + 0x8000u) >> 16;
}
static __device__ __forceinline__ uint32_t pk2(float a, float b) {
    union { float f; uint32_t u; } ca, cb; ca.f = a; cb.f = b;
    return ((ca.u + 0x8000u) >> 16) | ((cb.u + 0x8000u) & 0xffff0000u);
}

// ---------------- weight prep: frag-ready bf16, permuted k for L2/L3 -------
__global__ void prep_kernel(const float* __restrict__ W1, const float* __restrict__ cW1,
                            const float* __restrict__ b1, const float* __restrict__ cb1,
                            const float* __restrict__ W2, const float* __restrict__ cW2,
                            const float* __restrict__ W3, const float* __restrict__ cW3,
                            short* __restrict__ wp) {
    int b = blockIdx.x, lane = threadIdx.x;
    int nl = lane & 15, quad = lane >> 4;
    short frag[8];
    if (b < 60) {
        int e = b / 12, rem = b % 12, ks = rem / 4, nt = rem % 4;
        int n = nt * 16 + nl;
#pragma unroll
        for (int j = 0; j < 8; j++) {
            int k = ks * 32 + quad * 8 + j;
            float v = 0.f;
            if (k < 68)       v = (e < 4) ? W1[(e * 68 + k) * 64 + n] : cW1[k * 64 + n];
            else if (k == 68) v = (e < 4) ? b1[e * 64 + n] : cb1[n];
            frag[j] = (short)rna_hi(v);
        }
    } else if (b < 100) {
        int u = b - 60, e = u / 8, ks = (u % 8) / 4, nt = u % 4;
        int n = nt * 16 + nl;
#pragma unroll
        for (int j = 0; j < 8; j++) {
            int ka = (2 * ks + (j >> 2)) * 16 + quad * 4 + (j & 3);  // sigma
            frag[j] = (short)rna_hi((e < 4) ? W2[(e * 64 + ka) * 64 + n] : cW2[ka * 64 + n]);
        }
    } else {
        int u = b - 100;
#pragma unroll
        for (int j = 0; j < 8; j++) {
            int ks = (u < 8) ? (u & 1) : (u - 8);
            int ka = (2 * ks + (j >> 2)) * 16 + quad * 4 + (j & 3);  // sigma
            float v;
            if (u < 8) { int ee = u >> 1; v = W3[(ee * 64 + ka) * 16 + nl]; }
            else       { v = (nl == 0) ? cW3[ka] : 0.f; }
            frag[j] = (short)rna_hi(v);
        }
    }
    v8s pk = { frag[0], frag[1], frag[2], frag[3], frag[4], frag[5], frag[6], frag[7] };
    *(v8s*)(wp + (size_t)b * 512 + lane * 8) = pk;
}

// src slot (uint4 units) for staging net n, slot s; k selects region statically
static __device__ __forceinline__ int src_of(int n, int k, int s) {
    if (k < 3) return n * 768 + s;                 // L1: 12 blocks
    if (k < 5) return 3840 + n * 512 + (s - 768);  // L2: 8 blocks
    return 6400 + n * 128 + (s - 1280);            // L3: 2 blocks
}

// ---------------- main kernel ----------------------------------------------

__global__ __launch_bounds__(256, 2) void main_kernel(
    const float* __restrict__ obs, const float* __restrict__ gp,
    const int* __restrict__ hete, const short* __restrict__ wp,
    const float* __restrict__ b2, const float* __restrict__ b3,
    const float* __restrict__ cb2, const float* __restrict__ cb3,
    float* __restrict__ out)
{
    __shared__ __align__(16) uint4 buf[2][NSLOT];
    int tid = threadIdx.x, wv = tid >> 6, lane = tid & 63;
    int ml = lane & 15, quad = lane >> 4;
    int base = blockIdx.x * 256 + wv * 64;
    const uint4* w4 = (const uint4*)wp;

    // ---- stage net 0 into buf[0] ----
#pragma unroll
    for (int k = 0; k < 6; k++) {
        int s = tid + k * 256;
        if (k < 5 || tid < 128) buf[0][s] = w4[src_of(0, k, s)];
    }

    // ---- load token data (overlaps staging) ----
    v8s xf[2][4];   // x B-frags k 0..63, [ks][tt]
    v8s xg[4];      // k 64..95 frag: gp + bias-one (quad0)
    int tpv[4];
#pragma unroll
    for (int tt = 0; tt < 4; tt++) {
        int tok = base + tt * 16 + ml;
        tpv[tt] = hete[tok];
        const float* xr = obs + (size_t)tok * 64 + quad * 8;
#pragma unroll
        for (int ks = 0; ks < 2; ks++) {
            float4 a = *(const float4*)(xr + ks * 32);
            float4 c = *(const float4*)(xr + ks * 32 + 4);
            union { uint32_t u[4]; v8s s; } cv;
            cv.u[0] = pk2(a.x, a.y); cv.u[1] = pk2(a.z, a.w);
            cv.u[2] = pk2(c.x, c.y); cv.u[3] = pk2(c.z, c.w);
            xf[ks][tt] = cv.s;
        }
        union { uint32_t u[4]; v8s s; } cg;
        if (quad == 0) {
            float4 g = *(const float4*)(gp + (size_t)(base >> 7) * 4);
            cg.u[0] = pk2(g.x, g.y); cg.u[1] = pk2(g.z, g.w);
            cg.u[2] = 0x00003F80u;  // k=68 : bf16(1.0) -> b1 row of W1
            cg.u[3] = 0;
        } else { cg.u[0] = 0; cg.u[1] = 0; cg.u[2] = 0; cg.u[3] = 0; }
        xg[tt] = cg.s;
    }

    float cb3v = cb3[0];
    float oL[4][4], oV[4];
#pragma unroll
    for (int tt = 0; tt < 4; tt++) {
        oL[tt][0] = 0.f; oL[tt][1] = 0.f; oL[tt][2] = 0.f; oL[tt][3] = 0.f;
        oV[tt] = 0.f;
    }

    __syncthreads();

#pragma unroll 1
    for (int ne = 0; ne < 5; ne++) {   // 0..3 experts, 4 = critic
        // ---- issue prefetch of net ne+1 (drains during compute) ----
        uint4 pf[6];
        if (ne < 4) {
#pragma unroll
            for (int k = 0; k < 6; k++) {
                int s = tid + k * 256;
                if (k < 5 || tid < 128) pf[k] = w4[src_of(ne + 1, k, s)];
            }
        }

        const short* cw = (const short*)&buf[ne & 1][0];

        // ---- weights for this net from LDS (held in regs across tiles) ----
        v8s wa[3][4];
#pragma unroll
        for (int ks = 0; ks < 3; ks++)
#pragma unroll
            for (int nt = 0; nt < 4; nt++)
                wa[ks][nt] = *(const v8s*)(cw + (ks * 4 + nt) * 512 + lane * 8);
        v8s wa2[2][4];
#pragma unroll
        for (int ks2 = 0; ks2 < 2; ks2++)
#pragma unroll
            for (int nt = 0; nt < 4; nt++)
                wa2[ks2][nt] = *(const v8s*)(cw + 6144 + (ks2 * 4 + nt) * 512 + lane * 8);
        v8s w3f[2];
#pragma unroll
        for (int ks2 = 0; ks2 < 2; ks2++)
            w3f[ks2] = *(const v8s*)(cw + 10240 + ks2 * 512 + lane * 8);

        const float* B2 = (ne < 4) ? (b2 + ne * 64) : cb2;
        v4f bv2[4];
#pragma unroll
        for (int nt = 0; nt < 4; nt++)
            bv2[nt] = *(const v4f*)(B2 + nt * 16 + quad * 4);
        v4f b3f;
        if (ne < 4) b3f = *(const v4f*)(b3 + ne * 16 + quad * 4);
        else        b3f = (v4f){0.f, 0.f, 0.f, 0.f};

        // ---- per-tile full chain ----
#pragma unroll
        for (int tt = 0; tt < 4; tt++) {
            v4f acc[4];
#pragma unroll
            for (int nt = 0; nt < 4; nt++) acc[nt] = (v4f){0.f, 0.f, 0.f, 0.f};
#pragma unroll
            for (int ks = 0; ks < 3; ks++) {
                v8s xb = (ks < 2) ? xf[ks][tt] : xg[tt];
#pragma unroll
                for (int nt = 0; nt < 4; nt++)
                    acc[nt] = __builtin_amdgcn_mfma_f32_16x16x32_bf16(wa[ks][nt], xb, acc[nt], 0, 0, 0);
            }
            // pack h1 -> L2 B-frags (sigma layout), in-lane
            v8s hf[2];
#pragma unroll
            for (int ks2 = 0; ks2 < 2; ks2++) {
                union { uint32_t u[4]; v8s s; } cv;
                cv.u[0] = pk2(fmaxf(acc[2 * ks2][0], 0.f),     fmaxf(acc[2 * ks2][1], 0.f));
                cv.u[1] = pk2(fmaxf(acc[2 * ks2][2], 0.f),     fmaxf(acc[2 * ks2][3], 0.f));
                cv.u[2] = pk2(fmaxf(acc[2 * ks2 + 1][0], 0.f), fmaxf(acc[2 * ks2 + 1][1], 0.f));
                cv.u[3] = pk2(fmaxf(acc[2 * ks2 + 1][2], 0.f), fmaxf(acc[2 * ks2 + 1][3], 0.f));
                hf[ks2] = cv.s;
            }
            // layer 2, bias via acc-init
            v4f a2[4];
#pragma unroll
            for (int nt = 0; nt < 4; nt++) a2[nt] = bv2[nt];
#pragma unroll
            for (int ks2 = 0; ks2 < 2; ks2++)
#pragma unroll
                for (int nt = 0; nt < 4; nt++)
                    a2[nt] = __builtin_amdgcn_mfma_f32_16x16x32_bf16(wa2[ks2][nt], hf[ks2], a2[nt], 0, 0, 0);
            // pack h2 -> L3 B-frags
            v8s hf2[2];
#pragma unroll
            for (int ks2 = 0; ks2 < 2; ks2++) {
                union { uint32_t u[4]; v8s s; } cv;
                cv.u[0] = pk2(fmaxf(a2[2 * ks2][0], 0.f),     fmaxf(a2[2 * ks2][1], 0.f));
                cv.u[1] = pk2(fmaxf(a2[2 * ks2][2], 0.f),     fmaxf(a2[2 * ks2][3], 0.f));
                cv.u[2] = pk2(fmaxf(a2[2 * ks2 + 1][0], 0.f), fmaxf(a2[2 * ks2 + 1][1], 0.f));
                cv.u[3] = pk2(fmaxf(a2[2 * ks2 + 1][2], 0.f), fmaxf(a2[2 * ks2 + 1][3], 0.f));
                hf2[ks2] = cv.s;
            }
            // layer 3
            v4f a3 = b3f;
#pragma unroll
            for (int ks2 = 0; ks2 < 2; ks2++)
                a3 = __builtin_amdgcn_mfma_f32_16x16x32_bf16(w3f[ks2], hf2[ks2], a3, 0, 0, 0);

            if (ne < 4) {
#pragma unroll
                for (int rr = 0; rr < 4; rr++)
                    oL[tt][rr] = (tpv[tt] == ne) ? a3[rr] : oL[tt][rr];
            } else {
                oV[tt] = a3[0] + cb3v;   // valid on quad==0 (row 0)
            }
        }

        // ---- commit prefetch to LDS, sync ----
        if (ne < 4) {
#pragma unroll
            for (int k = 0; k < 6; k++) {
                int s = tid + k * 256;
                if (k < 5 || tid < 128) buf[(ne + 1) & 1][s] = pf[k];
            }
            __syncthreads();
        }
    }

    // ---- store: lane (quad,ml) owns logits quad*4..+3 of token ml ----
#pragma unroll
    for (int tt = 0; tt < 4; tt++) {
        int tok = base + tt * 16 + ml;
        size_t o = (size_t)tok * 17 + quad * 4;
        out[o + 0] = oL[tt][0];
        out[o + 1] = oL[tt][1];
        out[o + 2] = oL[tt][2];
        out[o + 3] = oL[tt][3];
        if (quad == 0) out[(size_t)tok * 17 + 16] = oV[tt];
    }
}

// ---------------------------------------------------------------------------

extern "C" void kernel_launch(void* const* d_in, const int* in_sizes, int n_in,
                              void* d_out, int out_size, void* d_ws, size_t ws_size,
                              hipStream_t stream) {
    const float* obs = (const float*)d_in[0];
    const int*  hete = (const int*)d_in[1];
    const float* gp  = (const float*)d_in[2];
    const float* W1  = (const float*)d_in[3];
    const float* b1  = (const float*)d_in[4];
    const float* W2  = (const float*)d_in[5];
    const float* b2  = (const float*)d_in[6];
    const float* W3  = (const float*)d_in[7];
    const float* b3  = (const float*)d_in[8];
    const float* cW1 = (const float*)d_in[9];
    const float* cb1 = (const float*)d_in[10];
    const float* cW2 = (const float*)d_in[11];
    const float* cb2 = (const float*)d_in[12];
    const float* cW3 = (const float*)d_in[13];
    const float* cb3 = (const float*)d_in[14];
    float* out = (float*)d_out;

    short* wp = (short*)d_ws;   // 56320 shorts

    prep_kernel<<<110,   64, 0, stream>>>(W1, cW1, b1, cb1, W2, cW2, W3, cW3, wp);
    main_kernel<<<1024, 256, 0, stream>>>(obs, gp, hete, wp,
                                          b2, b3, cb2, cb3, out);
}